// Round 6
// baseline (450.698 us; speedup 1.0000x reference)
//
#include <hip/hip_runtime.h>
#include <hip/hip_bf16.h>
#include <math.h>

// ---------------- types / helpers ----------------
typedef __attribute__((ext_vector_type(8))) short bf16x8;   // 8 bf16 in 4 VGPRs
typedef __attribute__((ext_vector_type(4))) float f32x4;
typedef __attribute__((ext_vector_type(4))) unsigned int u32x4;
typedef __attribute__((ext_vector_type(2))) unsigned int u32x2;

#define DEV static __device__ __forceinline__

constexpr int TT   = 2048;      // sequence length
constexpr int DDIM = 2048;      // model dim
constexpr int QKVN = 3072;      // 2048 q + 512 k + 512 v
constexpr int MROWS = 4096;     // B*T
constexpr float RSCALE = 0.08838834764831845f;  // 1/sqrt(128)
constexpr float LOG2E  = 1.4426950408889634f;
constexpr float SC2    = RSCALE * LOG2E;
constexpr float REPS   = 1.1920928955078125e-07f;

DEV unsigned short f2b(float f) {            // f32 -> bf16 RNE
  union { float f; unsigned int u; } v; v.f = f;
  unsigned int u = v.u;
  return (unsigned short)((u + 0x7fffu + ((u >> 16) & 1u)) >> 16);
}
DEV float b2f(unsigned short h) {
  union { unsigned int u; float f; } v; v.u = ((unsigned int)h) << 16;
  return v.f;
}
DEV f32x4 mfma16(bf16x8 a, bf16x8 b, f32x4 c) {
  return __builtin_amdgcn_mfma_f32_16x16x32_bf16(a, b, c, 0, 0, 0);
}
DEV void gload_lds16(const void* g, void* l) {
  __builtin_amdgcn_global_load_lds(
      (const __attribute__((address_space(1))) unsigned int*)g,
      (__attribute__((address_space(3))) unsigned int*)l, 16, 0, 0);
}
DEV unsigned int cvtpk(float lo, float hi) {  // packed f32->bf16 pair (1 instr)
  unsigned int r;
  asm("v_cvt_pk_bf16_f32 %0, %1, %2" : "=v"(r) : "v"(lo), "v"(hi));
  return r;
}
union PB { u32x4 u; bf16x8 b; };

// ---------------- 1. f32 -> bf16 convert ----------------
__global__ __launch_bounds__(256) void cvt_kernel(const float* __restrict__ in,
                                                  unsigned short* __restrict__ out,
                                                  int n4) {
  int i = blockIdx.x * 256 + threadIdx.x;
  if (i < n4) {
    float4 v = ((const float4*)in)[i];
    ushort4 o;
    o.x = f2b(v.x); o.y = f2b(v.y); o.z = f2b(v.z); o.w = f2b(v.w);
    ((ushort4*)out)[i] = o;
  }
}

// ---------- 2/5. 8-phase 256x256 GEMM (m201 template): C = A * B^T ----------
// BK=64, 8 waves (2M x 4N), per-wave C 128x64, dynamic LDS 128 KiB:
//   dbuf d: d*65536 + {A0:0, A1:16384, B0:32768, B1:49152}; half = [128][64] bf16.
// st_16x32 swizzle: byte = row*128 + (2*col ^ (((row>>2)&1)<<5)); applied via
// inverse-swizzled GLOBAL source (linear gload_lds dest) + swizzled ds_read.
// Stage schedule (step u): P0->A1(u+1) P1->B0(u+1) P2->B1(u+1) P3->A0(u+2);
// one counted vmcnt(2) per K-step (never 0 mid-loop).
template <typename CT>
__global__ __launch_bounds__(512, 2) void gemm256_bt(const unsigned short* __restrict__ A,
                                                     const unsigned short* __restrict__ B,
                                                     CT* __restrict__ C,
                                                     int N, int K, int nbx, int nwg) {
  extern __shared__ char smem[];
  const int tid = threadIdx.x;
  const int l = tid & 63, w = tid >> 6;
  const int lr = l & 15, lg = l >> 4;
  const int wm = w >> 2, wn = w & 3;

  // XCD swizzle (nwg % 8 == 0 for all our shapes -> bijective)
  const int cpx = nwg >> 3;
  const int sbid = ((int)blockIdx.x % 8) * cpx + (int)blockIdx.x / 8;
  const int bx = sbid % nbx, by = sbid / nbx;

  // ---- staging geometry: inverse-swizzled per-lane global source ----
  const int colb = ((l & 7) * 16) ^ (((l >> 5) & 1) << 5);   // bytes within row
  const unsigned short* Asrc = A + (long)(by * 256 + w * 8 + (l >> 3)) * K + (colb >> 1);
  const unsigned short* Bsrc = B + (long)(bx * 256 + w * 8 + (l >> 3)) * K + (colb >> 1);
  const int ldst_w = w * 1024;

  auto STAGE = [&](int ht, int t) {   // ht: 0=A0 1=A1 2=B0 3=B1
    const unsigned short* s0 = (ht < 2 ? Asrc : Bsrc) + (long)((ht & 1) * 128) * K + t * 64;
    char* d0 = smem + ((t & 1) * 65536 + ht * 16384 + ldst_w);
    gload_lds16(s0, d0);
    gload_lds16(s0 + (long)64 * K, d0 + 8192);
  };

  // ---- swizzled fragment reads ----
  const int swz_r = (lr & 4) << 3;    // 0 or 32
  auto LDA = [&](int db, int mi, int kk) -> bf16x8 {
    return *(const bf16x8*)(smem + db * 65536 + wm * 16384 +
                            (mi * 16 + lr) * 128 + ((kk * 64 + lg * 16) ^ swz_r));
  };
  auto LDB = [&](int db, int ni, int kk) -> bf16x8 {
    return *(const bf16x8*)(smem + db * 65536 + 32768 + (wn >> 1) * 16384 +
                            ((wn & 1) * 64 + ni * 16 + lr) * 128 +
                            ((kk * 64 + lg * 16) ^ swz_r));
  };

  f32x4 acc[8][4];
#pragma unroll
  for (int mi = 0; mi < 8; ++mi)
#pragma unroll
    for (int ni = 0; ni < 4; ++ni) acc[mi][ni] = f32x4{0.f, 0.f, 0.f, 0.f};

  const int NT = K >> 6;

  // ---- prologue: step0's 4 half-tiles + A0(1); wait for step0 only ----
  STAGE(0, 0); STAGE(1, 0); STAGE(2, 0); STAGE(3, 0); STAGE(0, 1);
  asm volatile("s_waitcnt vmcnt(2)" ::: "memory");
  __builtin_amdgcn_s_barrier();

  for (int u = 0; u < NT; ++u) {
    const int db = u & 1;
    bf16x8 af[4][2], bfr[2][2];

    // ======== P0: read A(mh0)+B(nh0), stage A1(u+1), MFMA quad (0,0) ========
#pragma unroll
    for (int mi = 0; mi < 4; ++mi) { af[mi][0] = LDA(db, mi, 0); af[mi][1] = LDA(db, mi, 1); }
#pragma unroll
    for (int ni = 0; ni < 2; ++ni) { bfr[ni][0] = LDB(db, ni, 0); bfr[ni][1] = LDB(db, ni, 1); }
    if (u + 1 < NT) STAGE(1, u + 1);
    asm volatile("s_waitcnt lgkmcnt(8)" ::: "memory");
    __builtin_amdgcn_s_barrier();
    asm volatile("s_waitcnt lgkmcnt(0)" ::: "memory");
    __builtin_amdgcn_sched_barrier(0);
    __builtin_amdgcn_s_setprio(1);
#pragma unroll
    for (int mi = 0; mi < 4; ++mi)
#pragma unroll
      for (int ni = 0; ni < 2; ++ni) {
        acc[mi][ni] = mfma16(af[mi][0], bfr[ni][0], acc[mi][ni]);
        acc[mi][ni] = mfma16(af[mi][1], bfr[ni][1], acc[mi][ni]);
      }
    __builtin_amdgcn_s_setprio(0);
    __builtin_amdgcn_sched_barrier(0);
    __builtin_amdgcn_s_barrier();

    // ======== P1: read B(nh1), stage B0(u+1), MFMA quad (0,1) ========
#pragma unroll
    for (int ni = 0; ni < 2; ++ni) { bfr[ni][0] = LDB(db, ni + 2, 0); bfr[ni][1] = LDB(db, ni + 2, 1); }
    if (u + 1 < NT) STAGE(2, u + 1);
    __builtin_amdgcn_s_barrier();
    asm volatile("s_waitcnt lgkmcnt(0)" ::: "memory");
    __builtin_amdgcn_sched_barrier(0);
    __builtin_amdgcn_s_setprio(1);
#pragma unroll
    for (int mi = 0; mi < 4; ++mi)
#pragma unroll
      for (int ni = 0; ni < 2; ++ni) {
        acc[mi][ni + 2] = mfma16(af[mi][0], bfr[ni][0], acc[mi][ni + 2]);
        acc[mi][ni + 2] = mfma16(af[mi][1], bfr[ni][1], acc[mi][ni + 2]);
      }
    __builtin_amdgcn_s_setprio(0);
    __builtin_amdgcn_sched_barrier(0);
    __builtin_amdgcn_s_barrier();

    // ======== P2: read A(mh1), stage B1(u+1), MFMA quad (1,1) ========
#pragma unroll
    for (int mi = 0; mi < 4; ++mi) { af[mi][0] = LDA(db, mi + 4, 0); af[mi][1] = LDA(db, mi + 4, 1); }
    if (u + 1 < NT) STAGE(3, u + 1);
    __builtin_amdgcn_s_barrier();
    asm volatile("s_waitcnt lgkmcnt(0)" ::: "memory");
    __builtin_amdgcn_sched_barrier(0);
    __builtin_amdgcn_s_setprio(1);
#pragma unroll
    for (int mi = 0; mi < 4; ++mi)
#pragma unroll
      for (int ni = 0; ni < 2; ++ni) {
        acc[mi + 4][ni + 2] = mfma16(af[mi][0], bfr[ni][0], acc[mi + 4][ni + 2]);
        acc[mi + 4][ni + 2] = mfma16(af[mi][1], bfr[ni][1], acc[mi + 4][ni + 2]);
      }
    __builtin_amdgcn_s_setprio(0);
    __builtin_amdgcn_sched_barrier(0);
    __builtin_amdgcn_s_barrier();

    // ======== P3: re-read B(nh0), stage A0(u+2), MFMA quad (1,0), vmcnt ====
#pragma unroll
    for (int ni = 0; ni < 2; ++ni) { bfr[ni][0] = LDB(db, ni, 0); bfr[ni][1] = LDB(db, ni, 1); }
    if (u + 2 < NT) STAGE(0, u + 2);
    __builtin_amdgcn_s_barrier();
    asm volatile("s_waitcnt lgkmcnt(0)" ::: "memory");
    __builtin_amdgcn_sched_barrier(0);
    __builtin_amdgcn_s_setprio(1);
#pragma unroll
    for (int mi = 0; mi < 4; ++mi)
#pragma unroll
      for (int ni = 0; ni < 2; ++ni) {
        acc[mi + 4][ni] = mfma16(af[mi][0], bfr[ni][0], acc[mi + 4][ni]);
        acc[mi + 4][ni] = mfma16(af[mi][1], bfr[ni][1], acc[mi + 4][ni]);
      }
    __builtin_amdgcn_s_setprio(0);
    __builtin_amdgcn_sched_barrier(0);
    if (u + 2 < NT) {           // newest half-tile (A0(u+2), 2 loads) may fly on
      asm volatile("s_waitcnt vmcnt(2)" ::: "memory");
    } else {
      asm volatile("s_waitcnt vmcnt(0)" ::: "memory");
    }
    __builtin_amdgcn_s_barrier();
  }

  // ---- epilogue ----
  const long crow0 = (long)by * 256 + wm * 128 + lg * 4;
  const long ccol0 = (long)bx * 256 + wn * 64 + lr;
#pragma unroll
  for (int mi = 0; mi < 8; ++mi)
#pragma unroll
    for (int ni = 0; ni < 4; ++ni)
#pragma unroll
      for (int r = 0; r < 4; ++r) {
        long row = crow0 + mi * 16 + r;
        long col = ccol0 + ni * 16;
        float val = acc[mi][ni][r];
        if constexpr (sizeof(CT) == 2)
          ((unsigned short*)C)[row * N + col] = f2b(val);
        else
          ((float*)C)[row * N + col] = val;
      }
}

// ---------------- 3. RoPE + RMSNorm (q heads 0..15, k heads 16..19) --------
__global__ __launch_bounds__(256) void rope_norm_kernel(unsigned short* __restrict__ qkv,
                                                        const float* __restrict__ qw,
                                                        const float* __restrict__ kw) {
  const int slot = blockIdx.x * 4 + (threadIdx.x >> 6);
  const int l = threadIdx.x & 63;
  const int bt = slot / 20;
  const int hs = slot - bt * 20;
  const int t = bt & (TT - 1);
  const bool isq = hs < 16;
  const int col0 = isq ? hs * 128 : 2048 + (hs - 16) * 128;
  const float* w = isq ? qw : kw;
  unsigned short* p = qkv + (long)bt * QKVN + col0;

  unsigned int pr = *(const unsigned int*)(p + 2 * l);
  float xr = b2f((unsigned short)(pr & 0xffffu));
  float xi = b2f((unsigned short)(pr >> 16));

  float ang = (float)t * exp2f(-0.207620509f * (float)l);
  float s = sinf(ang), c = cosf(ang);
  float orr = xr * c - xi * s;
  float oii = xr * s + xi * c;

  float ss = orr * orr + oii * oii;
#pragma unroll
  for (int d = 1; d < 64; d <<= 1) ss += __shfl_xor(ss, d);
  float sc = rsqrtf(ss * (1.f / 128.f) + REPS);

  unsigned int outw = ((unsigned int)f2b(oii * sc * w[2 * l + 1]) << 16) |
                      (unsigned int)f2b(orr * sc * w[2 * l]);
  *(unsigned int*)(p + 2 * l) = outw;
}

// ---------------- 4. causal flash attention (GQA 4:1) ----------------------
// (unchanged from round 5 — passing at 182 us)
__global__ __launch_bounds__(256) void fattn_kernel(const unsigned short* __restrict__ qkv,
                                                    unsigned short* __restrict__ y) {
  const int bx = blockIdx.x;
  const int bh = blockIdx.y;
  const int b = bh >> 4, h = bh & 15;
  const unsigned short* base = qkv + (long)b * TT * QKVN;
  const unsigned short* Qp = base + h * 128;
  const unsigned short* Kp = base + 2048 + (h >> 2) * 128;
  const unsigned short* Vp = base + 2560 + (h >> 2) * 128;
  const int tid = threadIdx.x;
  const int l = tid & 63, w = tid >> 6;
  const int lr = l & 15, lg = l >> 4;

  __shared__ char KsB[2][16384];             // swizzled K, 64x128 bf16
  __shared__ char VtB[2][16384];             // swizzled V^T, 128x64 bf16

  const int krow0 = tid >> 4;
  const int kcolb = ((tid & 15) * 16) ^ ((krow0 & 7) << 4);
  const unsigned short* Kg = Kp + (long)krow0 * QKVN + (kcolb >> 1);
  const int vm = tid & 15;
  const unsigned short* Vg = Vp + (long)(tid >> 4) * QKVN + vm * 8;
  const int lgk = ((lr & 7) << 4);           // K read swizzle

  for (int seg = 0; seg < 2; ++seg) {
    const int qb = seg ? bx : (31 - bx);
    const int qrow = qb * 64 + w * 16;
    const int ntiles = qb + 1;

    bf16x8 qf[4];
    {
      const unsigned short* qp = Qp + (long)(qrow + lr) * QKVN + lg * 8;
#pragma unroll
      for (int c = 0; c < 4; ++c) qf[c] = *(const bf16x8*)(qp + c * 32);
    }

    f32x4 o[8];
#pragma unroll
    for (int n = 0; n < 8; ++n) o[n] = f32x4{0.f, 0.f, 0.f, 0.f};
    float m = -__builtin_inff(), lsum = 0.f;

    __syncthreads();   // protect LDS from previous segment's readers

    u32x4 vr[4];
    {
      char* kdst = KsB[0] + (w * 64) * 16;
#pragma unroll
      for (int i = 0; i < 4; ++i)
        gload_lds16(Kg + (long)16 * i * QKVN, kdst + i * 4096);
#pragma unroll
      for (int i = 0; i < 4; ++i)
        vr[i] = *(const u32x4*)(Vg + (long)16 * i * QKVN);
      asm volatile("s_waitcnt vmcnt(0)" ::: "memory");
      char* vt = VtB[0];
#pragma unroll
      for (int i = 0; i < 4; ++i) {
        int kv2 = 2 * ((tid >> 4) + 16 * i);
        const unsigned short* tv = (const unsigned short*)&vr[i];
#pragma unroll
        for (int j = 0; j < 8; ++j) {
          int d = vm * 8 + j;
          int swz = (((d >> 1) ^ (d >> 3)) & 7) << 4;
          *(unsigned short*)(vt + d * 128 + (kv2 ^ swz)) = tv[j];
        }
      }
      asm volatile("s_waitcnt lgkmcnt(0)" ::: "memory");
      __builtin_amdgcn_sched_barrier(0);
      __builtin_amdgcn_s_barrier();
    }

    int cur = 0;
    for (int it = 0; it < ntiles; ++it) {
      const int kv0 = it * 64;
      const int nxt = cur ^ 1;
      const bool pfn = (it + 1 < ntiles);

      if (pfn) {
        const long adv = (long)(it + 1) * 64 * QKVN;
        char* kdst = KsB[nxt] + (w * 64) * 16;
#pragma unroll
        for (int i = 0; i < 4; ++i)
          gload_lds16(Kg + adv + (long)16 * i * QKVN, kdst + i * 4096);
#pragma unroll
        for (int i = 0; i < 4; ++i)
          vr[i] = *(const u32x4*)(Vg + adv + (long)16 * i * QKVN);
      }

      const char* KsC = KsB[cur];
      const char* VtC = VtB[cur];

      f32x4 sT[4];
      __builtin_amdgcn_s_setprio(1);
#pragma unroll
      for (int kb = 0; kb < 4; ++kb) {
        if (kv0 + kb * 16 <= qrow + 15) {
          f32x4 s = f32x4{0.f, 0.f, 0.f, 0.f};
#pragma unroll
          for (int c = 0; c < 4; ++c) {
            bf16x8 kf = *(const bf16x8*)(KsC + (kb * 16 + lr) * 256 +
                                         ((16 * lg + 64 * c) ^ lgk));
            s = mfma16(kf, qf[c], s);   // swapped operands
          }
          sT[kb] = s;
        } else {
          sT[kb] = f32x4{-__builtin_inff(), -__builtin_inff(),
                         -__builtin_inff(), -__builtin_inff()};
        }
      }
      __builtin_amdgcn_s_setprio(0);

      if (kv0 + 48 >= qrow) {
#pragma unroll
        for (int kb = 0; kb < 4; ++kb)
#pragma unroll
          for (int r = 0; r < 4; ++r) {
            int ks = kv0 + kb * 16 + 4 * lg + r;
            sT[kb][r] = (ks > qrow + lr) ? -__builtin_inff() : sT[kb][r];
          }
      }

      float pmax = -__builtin_inff();
#pragma unroll
      for (int kb = 0; kb < 4; ++kb)
#pragma unroll
        for (int r = 0; r < 4; ++r) pmax = fmaxf(pmax, sT[kb][r]);
      pmax = fmaxf(pmax, __shfl_xor(pmax, 16));
      pmax = fmaxf(pmax, __shfl_xor(pmax, 32));
      pmax *= SC2;

      if (!__all(pmax <= m + 8.f)) {
        float mn = fmaxf(m, pmax);
        float al = exp2f(m - mn);
        m = mn;
        lsum *= al;
        float ao[4];
#pragma unroll
        for (int r = 0; r < 4; ++r) ao[r] = __shfl(al, 20 * lg + r);
#pragma unroll
        for (int n = 0; n < 8; ++n)
#pragma unroll
          for (int r = 0; r < 4; ++r) o[n][r] *= ao[r];
      }

      float rs = 0.f;
      unsigned int pk[4][2];
#pragma unroll
      for (int kb = 0; kb < 4; ++kb) {
        float p0 = exp2f(sT[kb][0] * SC2 - m);
        float p1 = exp2f(sT[kb][1] * SC2 - m);
        float p2 = exp2f(sT[kb][2] * SC2 - m);
        float p3 = exp2f(sT[kb][3] * SC2 - m);
        rs += (p0 + p1) + (p2 + p3);
        pk[kb][0] = cvtpk(p0, p1);
        pk[kb][1] = cvtpk(p2, p3);
      }
      rs += __shfl_xor(rs, 16);
      rs += __shfl_xor(rs, 32);
      lsum += rs;

      __builtin_amdgcn_s_setprio(1);
#pragma unroll
      for (int c = 0; c < 2; ++c) {
        if (kv0 + c * 32 <= qrow + 15) {
          PB pb;
          pb.u = u32x4{pk[2 * c][0], pk[2 * c][1], pk[2 * c + 1][0], pk[2 * c + 1][1]};
#pragma unroll
          for (int n = 0; n < 8; ++n) {
            int d = n * 16 + lr;
            int gsw = (((d >> 1) ^ (d >> 3)) & 7) << 4;
            const char* vb = VtC + d * 128;
            u32x2 vlo = *(const u32x2*)(vb + ((64 * c + 8 * lg) ^ gsw));
            u32x2 vhi = *(const u32x2*)(vb + ((64 * c + 32 + 8 * lg) ^ gsw));
            PB vv; vv.u = u32x4{vlo[0], vlo[1], vhi[0], vhi[1]};
            o[n] = mfma16(pb.b, vv.b, o[n]);
          }
        }
      }
      __builtin_amdgcn_s_setprio(0);

      if (pfn) {
        asm volatile("s_waitcnt vmcnt(0)" ::: "memory");
        char* vt = VtB[nxt];
#pragma unroll
        for (int i = 0; i < 4; ++i) {
          int kv2 = 2 * ((tid >> 4) + 16 * i);
          const unsigned short* tv = (const unsigned short*)&vr[i];
#pragma unroll
          for (int j = 0; j < 8; ++j) {
            int d = vm * 8 + j;
            int swz = (((d >> 1) ^ (d >> 3)) & 7) << 4;
            *(unsigned short*)(vt + d * 128 + (kv2 ^ swz)) = tv[j];
          }
        }
        asm volatile("s_waitcnt lgkmcnt(0)" ::: "memory");
        __builtin_amdgcn_sched_barrier(0);
        __builtin_amdgcn_s_barrier();
      }
      cur = nxt;
    }

    float inv = 1.f / lsum;
    float io[4];
#pragma unroll
    for (int r = 0; r < 4; ++r) io[r] = __shfl(inv, 20 * lg + r);
    unsigned short* yp = y + (long)(b * TT + qrow) * DDIM + h * 128;
#pragma unroll
    for (int n = 0; n < 8; ++n)
#pragma unroll
      for (int r = 0; r < 4; ++r)
        yp[(long)(lg * 4 + r) * DDIM + n * 16 + lr] = f2b(o[n][r] * io[r]);
  }
}

// ---------------- launcher ----------------
extern "C" void kernel_launch(void* const* d_in, const int* in_sizes, int n_in,
                              void* d_out, int out_size, void* d_ws, size_t ws_size,
                              hipStream_t stream) {
  const float* x  = (const float*)d_in[0];
  const float* wq = (const float*)d_in[1];
  const float* wk = (const float*)d_in[2];
  const float* wv = (const float*)d_in[3];
  const float* wo = (const float*)d_in[4];
  const float* qw = (const float*)d_in[5];
  const float* kw = (const float*)d_in[6];
  float* out = (float*)d_out;

  unsigned short* xb   = (unsigned short*)d_ws;                 // 4096x2048
  unsigned short* wcat = xb + (size_t)MROWS * DDIM;             // 3072x2048
  unsigned short* wob  = wcat + (size_t)QKVN * DDIM;            // 2048x2048
  unsigned short* qkv  = wob + (size_t)DDIM * DDIM;             // 4096x3072
  unsigned short* yb   = qkv + (size_t)MROWS * QKVN;            // 4096x2048

  // allow 128 KiB dynamic LDS (idempotent host-side attr set; not a stream op)
  (void)hipFuncSetAttribute((const void*)gemm256_bt<unsigned short>,
                            hipFuncAttributeMaxDynamicSharedMemorySize, 131072);
  (void)hipFuncSetAttribute((const void*)gemm256_bt<float>,
                            hipFuncAttributeMaxDynamicSharedMemorySize, 131072);

  auto cvt = [&](const float* src, unsigned short* dst, long n) {
    int n4 = (int)(n / 4);
    cvt_kernel<<<(n4 + 255) / 256, 256, 0, stream>>>(src, dst, n4);
  };
  cvt(x,  xb,   (long)MROWS * DDIM);
  cvt(wq, wcat,                         (long)2048 * 2048);
  cvt(wk, wcat + (size_t)2048 * 2048,   (long)512 * 2048);
  cvt(wv, wcat + (size_t)2560 * 2048,   (long)512 * 2048);
  cvt(wo, wob,  (long)2048 * 2048);

  // GEMM1: qkv = xb * wcat^T   (4096 x 3072, K=2048) -> 16x12 = 192 blocks
  gemm256_bt<unsigned short><<<dim3(192), dim3(512), 131072, stream>>>(
      xb, wcat, qkv, QKVN, DDIM, 12, 192);

  rope_norm_kernel<<<(MROWS * 20) / 4, 256, 0, stream>>>(qkv, qw, kw);

  dim3 g2(16, 32);
  fattn_kernel<<<g2, 256, 0, stream>>>(qkv, yb);

  // GEMM2: out = yb * wob^T   (4096 x 2048, K=2048) -> 16x8 = 128 blocks
  gemm256_bt<float><<<dim3(128), dim3(512), 131072, stream>>>(
      yb, wob, out, DDIM, DDIM, 8, 128);
}

// Round 7
// 449.342 us; speedup vs baseline: 1.0030x; 1.0030x over previous
//
#include <hip/hip_runtime.h>
#include <hip/hip_bf16.h>
#include <math.h>

// ---------------- types / helpers ----------------
typedef __attribute__((ext_vector_type(8))) short bf16x8;   // 8 bf16 in 4 VGPRs
typedef __attribute__((ext_vector_type(4))) float f32x4;
typedef __attribute__((ext_vector_type(4))) unsigned int u32x4;
typedef __attribute__((ext_vector_type(2))) unsigned int u32x2;

#define DEV static __device__ __forceinline__

constexpr int TT   = 2048;      // sequence length
constexpr int DDIM = 2048;      // model dim
constexpr int QKVN = 3072;      // 2048 q + 512 k + 512 v
constexpr int MROWS = 4096;     // B*T
constexpr float RSCALE = 0.08838834764831845f;  // 1/sqrt(128)
constexpr float LOG2E  = 1.4426950408889634f;
constexpr float SC2    = RSCALE * LOG2E;
constexpr float REPS   = 1.1920928955078125e-07f;

DEV unsigned short f2b(float f) {            // f32 -> bf16 RNE
  union { float f; unsigned int u; } v; v.f = f;
  unsigned int u = v.u;
  return (unsigned short)((u + 0x7fffu + ((u >> 16) & 1u)) >> 16);
}
DEV float b2f(unsigned short h) {
  union { unsigned int u; float f; } v; v.u = ((unsigned int)h) << 16;
  return v.f;
}
DEV f32x4 mfma16(bf16x8 a, bf16x8 b, f32x4 c) {
  return __builtin_amdgcn_mfma_f32_16x16x32_bf16(a, b, c, 0, 0, 0);
}
DEV void gload_lds16(const void* g, void* l) {
  __builtin_amdgcn_global_load_lds(
      (const __attribute__((address_space(1))) unsigned int*)g,
      (__attribute__((address_space(3))) unsigned int*)l, 16, 0, 0);
}
DEV unsigned int cvtpk(float lo, float hi) {  // packed f32->bf16 pair (1 instr)
  unsigned int r;
  asm("v_cvt_pk_bf16_f32 %0, %1, %2" : "=v"(r) : "v"(lo), "v"(hi));
  return r;
}
union PB { u32x4 u; bf16x8 b; };

// ---------------- 1. f32 -> bf16 convert ----------------
__global__ __launch_bounds__(256) void cvt_kernel(const float* __restrict__ in,
                                                  unsigned short* __restrict__ out,
                                                  int n4) {
  int i = blockIdx.x * 256 + threadIdx.x;
  if (i < n4) {
    float4 v = ((const float4*)in)[i];
    ushort4 o;
    o.x = f2b(v.x); o.y = f2b(v.y); o.z = f2b(v.z); o.w = f2b(v.w);
    ((ushort4*)out)[i] = o;
  }
}

// ---------- 2/5. 8-phase 256x256 GEMM (m201 template): C = A * B^T ----------
// (unchanged from round 6 — measured neutral vs 2-phase; re-diagnose once
//  visible in top-5 counters)
template <typename CT>
__global__ __launch_bounds__(512, 2) void gemm256_bt(const unsigned short* __restrict__ A,
                                                     const unsigned short* __restrict__ B,
                                                     CT* __restrict__ C,
                                                     int N, int K, int nbx, int nwg) {
  extern __shared__ char smem[];
  const int tid = threadIdx.x;
  const int l = tid & 63, w = tid >> 6;
  const int lr = l & 15, lg = l >> 4;
  const int wm = w >> 2, wn = w & 3;

  const int cpx = nwg >> 3;
  const int sbid = ((int)blockIdx.x % 8) * cpx + (int)blockIdx.x / 8;
  const int bx = sbid % nbx, by = sbid / nbx;

  const int colb = ((l & 7) * 16) ^ (((l >> 5) & 1) << 5);   // bytes within row
  const unsigned short* Asrc = A + (long)(by * 256 + w * 8 + (l >> 3)) * K + (colb >> 1);
  const unsigned short* Bsrc = B + (long)(bx * 256 + w * 8 + (l >> 3)) * K + (colb >> 1);
  const int ldst_w = w * 1024;

  auto STAGE = [&](int ht, int t) {   // ht: 0=A0 1=A1 2=B0 3=B1
    const unsigned short* s0 = (ht < 2 ? Asrc : Bsrc) + (long)((ht & 1) * 128) * K + t * 64;
    char* d0 = smem + ((t & 1) * 65536 + ht * 16384 + ldst_w);
    gload_lds16(s0, d0);
    gload_lds16(s0 + (long)64 * K, d0 + 8192);
  };

  const int swz_r = (lr & 4) << 3;    // 0 or 32
  auto LDA = [&](int db, int mi, int kk) -> bf16x8 {
    return *(const bf16x8*)(smem + db * 65536 + wm * 16384 +
                            (mi * 16 + lr) * 128 + ((kk * 64 + lg * 16) ^ swz_r));
  };
  auto LDB = [&](int db, int ni, int kk) -> bf16x8 {
    return *(const bf16x8*)(smem + db * 65536 + 32768 + (wn >> 1) * 16384 +
                            ((wn & 1) * 64 + ni * 16 + lr) * 128 +
                            ((kk * 64 + lg * 16) ^ swz_r));
  };

  f32x4 acc[8][4];
#pragma unroll
  for (int mi = 0; mi < 8; ++mi)
#pragma unroll
    for (int ni = 0; ni < 4; ++ni) acc[mi][ni] = f32x4{0.f, 0.f, 0.f, 0.f};

  const int NT = K >> 6;

  STAGE(0, 0); STAGE(1, 0); STAGE(2, 0); STAGE(3, 0); STAGE(0, 1);
  asm volatile("s_waitcnt vmcnt(2)" ::: "memory");
  __builtin_amdgcn_s_barrier();

  for (int u = 0; u < NT; ++u) {
    const int db = u & 1;
    bf16x8 af[4][2], bfr[2][2];

    // ======== P0 ========
#pragma unroll
    for (int mi = 0; mi < 4; ++mi) { af[mi][0] = LDA(db, mi, 0); af[mi][1] = LDA(db, mi, 1); }
#pragma unroll
    for (int ni = 0; ni < 2; ++ni) { bfr[ni][0] = LDB(db, ni, 0); bfr[ni][1] = LDB(db, ni, 1); }
    if (u + 1 < NT) STAGE(1, u + 1);
    asm volatile("s_waitcnt lgkmcnt(8)" ::: "memory");
    __builtin_amdgcn_s_barrier();
    asm volatile("s_waitcnt lgkmcnt(0)" ::: "memory");
    __builtin_amdgcn_sched_barrier(0);
    __builtin_amdgcn_s_setprio(1);
#pragma unroll
    for (int mi = 0; mi < 4; ++mi)
#pragma unroll
      for (int ni = 0; ni < 2; ++ni) {
        acc[mi][ni] = mfma16(af[mi][0], bfr[ni][0], acc[mi][ni]);
        acc[mi][ni] = mfma16(af[mi][1], bfr[ni][1], acc[mi][ni]);
      }
    __builtin_amdgcn_s_setprio(0);
    __builtin_amdgcn_sched_barrier(0);
    __builtin_amdgcn_s_barrier();

    // ======== P1 ========
#pragma unroll
    for (int ni = 0; ni < 2; ++ni) { bfr[ni][0] = LDB(db, ni + 2, 0); bfr[ni][1] = LDB(db, ni + 2, 1); }
    if (u + 1 < NT) STAGE(2, u + 1);
    __builtin_amdgcn_s_barrier();
    asm volatile("s_waitcnt lgkmcnt(0)" ::: "memory");
    __builtin_amdgcn_sched_barrier(0);
    __builtin_amdgcn_s_setprio(1);
#pragma unroll
    for (int mi = 0; mi < 4; ++mi)
#pragma unroll
      for (int ni = 0; ni < 2; ++ni) {
        acc[mi][ni + 2] = mfma16(af[mi][0], bfr[ni][0], acc[mi][ni + 2]);
        acc[mi][ni + 2] = mfma16(af[mi][1], bfr[ni][1], acc[mi][ni + 2]);
      }
    __builtin_amdgcn_s_setprio(0);
    __builtin_amdgcn_sched_barrier(0);
    __builtin_amdgcn_s_barrier();

    // ======== P2 ========
#pragma unroll
    for (int mi = 0; mi < 4; ++mi) { af[mi][0] = LDA(db, mi + 4, 0); af[mi][1] = LDA(db, mi + 4, 1); }
    if (u + 1 < NT) STAGE(3, u + 1);
    __builtin_amdgcn_s_barrier();
    asm volatile("s_waitcnt lgkmcnt(0)" ::: "memory");
    __builtin_amdgcn_sched_barrier(0);
    __builtin_amdgcn_s_setprio(1);
#pragma unroll
    for (int mi = 0; mi < 4; ++mi)
#pragma unroll
      for (int ni = 0; ni < 2; ++ni) {
        acc[mi + 4][ni + 2] = mfma16(af[mi][0], bfr[ni][0], acc[mi + 4][ni + 2]);
        acc[mi + 4][ni + 2] = mfma16(af[mi][1], bfr[ni][1], acc[mi + 4][ni + 2]);
      }
    __builtin_amdgcn_s_setprio(0);
    __builtin_amdgcn_sched_barrier(0);
    __builtin_amdgcn_s_barrier();

    // ======== P3 ========
#pragma unroll
    for (int ni = 0; ni < 2; ++ni) { bfr[ni][0] = LDB(db, ni, 0); bfr[ni][1] = LDB(db, ni, 1); }
    if (u + 2 < NT) STAGE(0, u + 2);
    __builtin_amdgcn_s_barrier();
    asm volatile("s_waitcnt lgkmcnt(0)" ::: "memory");
    __builtin_amdgcn_sched_barrier(0);
    __builtin_amdgcn_s_setprio(1);
#pragma unroll
    for (int mi = 0; mi < 4; ++mi)
#pragma unroll
      for (int ni = 0; ni < 2; ++ni) {
        acc[mi + 4][ni] = mfma16(af[mi][0], bfr[ni][0], acc[mi + 4][ni]);
        acc[mi + 4][ni] = mfma16(af[mi][1], bfr[ni][1], acc[mi + 4][ni]);
      }
    __builtin_amdgcn_s_setprio(0);
    __builtin_amdgcn_sched_barrier(0);
    if (u + 2 < NT) {
      asm volatile("s_waitcnt vmcnt(2)" ::: "memory");
    } else {
      asm volatile("s_waitcnt vmcnt(0)" ::: "memory");
    }
    __builtin_amdgcn_s_barrier();
  }

  const long crow0 = (long)by * 256 + wm * 128 + lg * 4;
  const long ccol0 = (long)bx * 256 + wn * 64 + lr;
#pragma unroll
  for (int mi = 0; mi < 8; ++mi)
#pragma unroll
    for (int ni = 0; ni < 4; ++ni)
#pragma unroll
      for (int r = 0; r < 4; ++r) {
        long row = crow0 + mi * 16 + r;
        long col = ccol0 + ni * 16;
        float val = acc[mi][ni][r];
        if constexpr (sizeof(CT) == 2)
          ((unsigned short*)C)[row * N + col] = f2b(val);
        else
          ((float*)C)[row * N + col] = val;
      }
}

// ---------------- 3. RoPE + RMSNorm (q heads 0..15, k heads 16..19) --------
__global__ __launch_bounds__(256) void rope_norm_kernel(unsigned short* __restrict__ qkv,
                                                        const float* __restrict__ qw,
                                                        const float* __restrict__ kw) {
  const int slot = blockIdx.x * 4 + (threadIdx.x >> 6);
  const int l = threadIdx.x & 63;
  const int bt = slot / 20;
  const int hs = slot - bt * 20;
  const int t = bt & (TT - 1);
  const bool isq = hs < 16;
  const int col0 = isq ? hs * 128 : 2048 + (hs - 16) * 128;
  const float* w = isq ? qw : kw;
  unsigned short* p = qkv + (long)bt * QKVN + col0;

  unsigned int pr = *(const unsigned int*)(p + 2 * l);
  float xr = b2f((unsigned short)(pr & 0xffffu));
  float xi = b2f((unsigned short)(pr >> 16));

  float ang = (float)t * exp2f(-0.207620509f * (float)l);
  float s = sinf(ang), c = cosf(ang);
  float orr = xr * c - xi * s;
  float oii = xr * s + xi * c;

  float ss = orr * orr + oii * oii;
#pragma unroll
  for (int d = 1; d < 64; d <<= 1) ss += __shfl_xor(ss, d);
  float sc = rsqrtf(ss * (1.f / 128.f) + REPS);

  unsigned int outw = ((unsigned int)f2b(oii * sc * w[2 * l + 1]) << 16) |
                      (unsigned int)f2b(orr * sc * w[2 * l]);
  *(unsigned int*)(p + 2 * l) = outw;
}

// ---------------- 4. causal flash attention (GQA 4:1) ----------------------
// grid (32, B*16): one qb per block, qb = 31-bx (longest dispatched first,
// triangle self-balances via 3-blocks/CU backfill). K double-buffered
// (gload_lds), V SINGLE-buffered (reg-staged, written after PV + barrier).
// LDS 48 KiB -> 3 blocks/CU (12 waves) vs round-6's 2 (8 waves).
__global__ __launch_bounds__(256) void fattn_kernel(const unsigned short* __restrict__ qkv,
                                                    unsigned short* __restrict__ y) {
  const int qb = 31 - (int)blockIdx.x;       // longest first
  const int bh = blockIdx.y;
  const int b = bh >> 4, h = bh & 15;
  const unsigned short* base = qkv + (long)b * TT * QKVN;
  const unsigned short* Qp = base + h * 128;
  const unsigned short* Kp = base + 2048 + (h >> 2) * 128;
  const unsigned short* Vp = base + 2560 + (h >> 2) * 128;
  const int tid = threadIdx.x;
  const int l = tid & 63, w = tid >> 6;
  const int lr = l & 15, lg = l >> 4;
  const int qrow = qb * 64 + w * 16;
  const int ntiles = qb + 1;

  __shared__ char KsB[2][16384];             // swizzled K, 64x128 bf16 (dbuf)
  __shared__ char Vt[16384];                 // swizzled V^T, 128x64 bf16 (single)

  const int krow0 = tid >> 4;
  const int kcolb = ((tid & 15) * 16) ^ ((krow0 & 7) << 4);
  const unsigned short* Kg = Kp + (long)krow0 * QKVN + (kcolb >> 1);
  const int vm = tid & 15;
  const unsigned short* Vg = Vp + (long)(tid >> 4) * QKVN + vm * 8;
  const int lgk = ((lr & 7) << 4);           // K read swizzle

  bf16x8 qf[4];
  {
    const unsigned short* qp = Qp + (long)(qrow + lr) * QKVN + lg * 8;
#pragma unroll
    for (int c = 0; c < 4; ++c) qf[c] = *(const bf16x8*)(qp + c * 32);
  }

  f32x4 o[8];
#pragma unroll
  for (int n = 0; n < 8; ++n) o[n] = f32x4{0.f, 0.f, 0.f, 0.f};
  float m = -__builtin_inff(), lsum = 0.f;

  u32x4 vr[4];
  // ---- prologue: K(0) -> KsB[0], V(0) -> regs -> Vt ----
  {
    char* kdst = KsB[0] + (w * 64) * 16;
#pragma unroll
    for (int i = 0; i < 4; ++i)
      gload_lds16(Kg + (long)16 * i * QKVN, kdst + i * 4096);
#pragma unroll
    for (int i = 0; i < 4; ++i)
      vr[i] = *(const u32x4*)(Vg + (long)16 * i * QKVN);
    asm volatile("s_waitcnt vmcnt(0)" ::: "memory");
#pragma unroll
    for (int i = 0; i < 4; ++i) {
      int kv2 = 2 * ((tid >> 4) + 16 * i);
      const unsigned short* tv = (const unsigned short*)&vr[i];
#pragma unroll
      for (int j = 0; j < 8; ++j) {
        int d = vm * 8 + j;
        int swz = (((d >> 1) ^ (d >> 3)) & 7) << 4;
        *(unsigned short*)(Vt + d * 128 + (kv2 ^ swz)) = tv[j];
      }
    }
    asm volatile("s_waitcnt lgkmcnt(0)" ::: "memory");
    __builtin_amdgcn_sched_barrier(0);
    __builtin_amdgcn_s_barrier();
  }

  int cur = 0;
  for (int it = 0; it < ntiles; ++it) {
    const int kv0 = it * 64;
    const int nxt = cur ^ 1;
    const bool pfn = (it + 1 < ntiles);

    // ---- issue next-tile loads (fly during compute) ----
    if (pfn) {
      const long adv = (long)(it + 1) * 64 * QKVN;
      char* kdst = KsB[nxt] + (w * 64) * 16;
#pragma unroll
      for (int i = 0; i < 4; ++i)
        gload_lds16(Kg + adv + (long)16 * i * QKVN, kdst + i * 4096);
#pragma unroll
      for (int i = 0; i < 4; ++i)
        vr[i] = *(const u32x4*)(Vg + adv + (long)16 * i * QKVN);
    }

    const char* KsC = KsB[cur];

    // ---- S^T = K Q^T : lane -> S[qrow+lr][kv0+16kb+4lg+r] ----
    f32x4 sT[4];
    __builtin_amdgcn_s_setprio(1);
#pragma unroll
    for (int kb = 0; kb < 4; ++kb) {
      if (kv0 + kb * 16 <= qrow + 15) {
        f32x4 s = f32x4{0.f, 0.f, 0.f, 0.f};
#pragma unroll
        for (int c = 0; c < 4; ++c) {
          bf16x8 kf = *(const bf16x8*)(KsC + (kb * 16 + lr) * 256 +
                                       ((16 * lg + 64 * c) ^ lgk));
          s = mfma16(kf, qf[c], s);   // swapped operands
        }
        sT[kb] = s;
      } else {
        sT[kb] = f32x4{-__builtin_inff(), -__builtin_inff(),
                       -__builtin_inff(), -__builtin_inff()};
      }
    }
    __builtin_amdgcn_s_setprio(0);

    // ---- causal mask; needed iff kv0+63 > qrow  <=>  kv0+48 >= qrow ----
    if (kv0 + 48 >= qrow) {
#pragma unroll
      for (int kb = 0; kb < 4; ++kb)
#pragma unroll
        for (int r = 0; r < 4; ++r) {
          int ks = kv0 + kb * 16 + 4 * lg + r;
          sT[kb][r] = (ks > qrow + lr) ? -__builtin_inff() : sT[kb][r];
        }
    }

    // ---- in-register online softmax (row = lane's lr) ----
    float pmax = -__builtin_inff();
#pragma unroll
    for (int kb = 0; kb < 4; ++kb)
#pragma unroll
      for (int r = 0; r < 4; ++r) pmax = fmaxf(pmax, sT[kb][r]);
    pmax = fmaxf(pmax, __shfl_xor(pmax, 16));
    pmax = fmaxf(pmax, __shfl_xor(pmax, 32));
    pmax *= SC2;

    if (!__all(pmax <= m + 8.f)) {     // defer-max: rescale rarely
      float mn = fmaxf(m, pmax);
      float al = exp2f(m - mn);
      m = mn;
      lsum *= al;
      float ao[4];
#pragma unroll
      for (int r = 0; r < 4; ++r) ao[r] = __shfl(al, 20 * lg + r);
#pragma unroll
      for (int n = 0; n < 8; ++n)
#pragma unroll
        for (int r = 0; r < 4; ++r) o[n][r] *= ao[r];
    }

    float rs = 0.f;
    unsigned int pk[4][2];
#pragma unroll
    for (int kb = 0; kb < 4; ++kb) {
      float p0 = exp2f(sT[kb][0] * SC2 - m);
      float p1 = exp2f(sT[kb][1] * SC2 - m);
      float p2 = exp2f(sT[kb][2] * SC2 - m);
      float p3 = exp2f(sT[kb][3] * SC2 - m);
      rs += (p0 + p1) + (p2 + p3);
      pk[kb][0] = cvtpk(p0, p1);
      pk[kb][1] = cvtpk(p2, p3);
    }
    rs += __shfl_xor(rs, 16);
    rs += __shfl_xor(rs, 32);
    lsum += rs;

    // ---- O += P V (sigma-permuted k-order on both operands) ----
    __builtin_amdgcn_s_setprio(1);
#pragma unroll
    for (int c = 0; c < 2; ++c) {
      if (kv0 + c * 32 <= qrow + 15) {
        PB pb;
        pb.u = u32x4{pk[2 * c][0], pk[2 * c][1], pk[2 * c + 1][0], pk[2 * c + 1][1]};
#pragma unroll
        for (int n = 0; n < 8; ++n) {
          int d = n * 16 + lr;
          int gsw = (((d >> 1) ^ (d >> 3)) & 7) << 4;
          const char* vb = Vt + d * 128;
          u32x2 vlo = *(const u32x2*)(vb + ((64 * c + 8 * lg) ^ gsw));
          u32x2 vhi = *(const u32x2*)(vb + ((64 * c + 32 + 8 * lg) ^ gsw));
          PB vv; vv.u = u32x4{vlo[0], vlo[1], vhi[0], vhi[1]};
          o[n] = mfma16(pb.b, vv.b, o[n]);
        }
      }
    }
    __builtin_amdgcn_s_setprio(0);

    // ---- single-buffer V handoff: all waves done with Vt, then overwrite --
    if (pfn) {
      asm volatile("s_waitcnt lgkmcnt(0)" ::: "memory");
      __builtin_amdgcn_s_barrier();            // #1: PV reads of Vt complete
      asm volatile("s_waitcnt vmcnt(0)" ::: "memory");  // vr + K(nxt) landed
#pragma unroll
      for (int i = 0; i < 4; ++i) {
        int kv2 = 2 * ((tid >> 4) + 16 * i);
        const unsigned short* tv = (const unsigned short*)&vr[i];
#pragma unroll
        for (int j = 0; j < 8; ++j) {
          int d = vm * 8 + j;
          int swz = (((d >> 1) ^ (d >> 3)) & 7) << 4;
          *(unsigned short*)(Vt + d * 128 + (kv2 ^ swz)) = tv[j];
        }
      }
      asm volatile("s_waitcnt lgkmcnt(0)" ::: "memory");
      __builtin_amdgcn_sched_barrier(0);
      __builtin_amdgcn_s_barrier();            // #2: Vt(t+1)/K(t+1) ready
    }
    cur = nxt;
  }

  // ---- epilogue ----
  float inv = 1.f / lsum;
  float io[4];
#pragma unroll
  for (int r = 0; r < 4; ++r) io[r] = __shfl(inv, 20 * lg + r);
  unsigned short* yp = y + (long)(b * TT + qrow) * DDIM + h * 128;
#pragma unroll
  for (int n = 0; n < 8; ++n)
#pragma unroll
    for (int r = 0; r < 4; ++r)
      yp[(long)(lg * 4 + r) * DDIM + n * 16 + lr] = f2b(o[n][r] * io[r]);
}

// ---------------- launcher ----------------
extern "C" void kernel_launch(void* const* d_in, const int* in_sizes, int n_in,
                              void* d_out, int out_size, void* d_ws, size_t ws_size,
                              hipStream_t stream) {
  const float* x  = (const float*)d_in[0];
  const float* wq = (const float*)d_in[1];
  const float* wk = (const float*)d_in[2];
  const float* wv = (const float*)d_in[3];
  const float* wo = (const float*)d_in[4];
  const float* qw = (const float*)d_in[5];
  const float* kw = (const float*)d_in[6];
  float* out = (float*)d_out;

  unsigned short* xb   = (unsigned short*)d_ws;                 // 4096x2048
  unsigned short* wcat = xb + (size_t)MROWS * DDIM;             // 3072x2048
  unsigned short* wob  = wcat + (size_t)QKVN * DDIM;            // 2048x2048
  unsigned short* qkv  = wob + (size_t)DDIM * DDIM;             // 4096x3072
  unsigned short* yb   = qkv + (size_t)MROWS * QKVN;            // 4096x2048

  (void)hipFuncSetAttribute((const void*)gemm256_bt<unsigned short>,
                            hipFuncAttributeMaxDynamicSharedMemorySize, 131072);
  (void)hipFuncSetAttribute((const void*)gemm256_bt<float>,
                            hipFuncAttributeMaxDynamicSharedMemorySize, 131072);

  auto cvt = [&](const float* src, unsigned short* dst, long n) {
    int n4 = (int)(n / 4);
    cvt_kernel<<<(n4 + 255) / 256, 256, 0, stream>>>(src, dst, n4);
  };
  cvt(x,  xb,   (long)MROWS * DDIM);
  cvt(wq, wcat,                         (long)2048 * 2048);
  cvt(wk, wcat + (size_t)2048 * 2048,   (long)512 * 2048);
  cvt(wv, wcat + (size_t)2560 * 2048,   (long)512 * 2048);
  cvt(wo, wob,  (long)2048 * 2048);

  // GEMM1: qkv = xb * wcat^T   (4096 x 3072, K=2048) -> 16x12 = 192 blocks
  gemm256_bt<unsigned short><<<dim3(192), dim3(512), 131072, stream>>>(
      xb, wcat, qkv, QKVN, DDIM, 12, 192);

  rope_norm_kernel<<<(MROWS * 20) / 4, 256, 0, stream>>>(qkv, qw, kw);

  dim3 g2(32, 32);
  fattn_kernel<<<g2, 256, 0, stream>>>(qkv, yb);

  // GEMM2: out = yb * wob^T   (4096 x 2048, K=2048) -> 16x8 = 128 blocks
  gemm256_bt<float><<<dim3(128), dim3(512), 131072, stream>>>(
      yb, wob, out, DDIM, DDIM, 8, 128);
}